// Round 7
// baseline (6048.846 us; speedup 1.0000x reference)
//
#include <hip/hip_runtime.h>

#define TT 2048
#define DD 8
#define HH 64

// Pin to a VGPR: opaque to the optimizer, so the invariant global load feeding
// it cannot be re-materialized (sunk) into the loop — the round-4/6 disease
// (named scalars re-loaded per step -> 33.6 GB FETCH). Demand here is ~90 regs,
// safely inside the 128-VGPR class, so pinning cannot trigger round-5's spill.
#define PIN(v) asm("" : "+v"(v))

__device__ __forceinline__ float sigm(float x)  { return 1.0f / (1.0f + __expf(-x)); }
__device__ __forceinline__ float tanh_(float x) { return 1.0f - 2.0f / (__expf(2.0f * x) + 1.0f); }

// ---- 16 named weight scalars per matrix ----
#define DECLW(P) float P##0,P##1,P##2,P##3,P##4,P##5,P##6,P##7, \
                       P##8,P##9,P##10,P##11,P##12,P##13,P##14,P##15;
#define LOADW(P, ptr) { \
  const float4 q0 = *(const float4*)(ptr); \
  const float4 q1 = *(const float4*)((ptr) + 4); \
  const float4 q2 = *(const float4*)((ptr) + 8); \
  const float4 q3 = *(const float4*)((ptr) + 12); \
  P##0=q0.x; P##1=q0.y; P##2=q0.z; P##3=q0.w; \
  P##4=q1.x; P##5=q1.y; P##6=q1.z; P##7=q1.w; \
  P##8=q2.x; P##9=q2.y; P##10=q2.z; P##11=q2.w; \
  P##12=q3.x; P##13=q3.y; P##14=q3.z; P##15=q3.w; \
  PIN(P##0); PIN(P##1); PIN(P##2); PIN(P##3); \
  PIN(P##4); PIN(P##5); PIN(P##6); PIN(P##7); \
  PIN(P##8); PIN(P##9); PIN(P##10); PIN(P##11); \
  PIN(P##12); PIN(P##13); PIN(P##14); PIN(P##15); }

// one k-pair of phase C: h quads via uniform-address ds_read_b128 (broadcast,
// bank-free); 12 FMA from pinned registers; 8 accumulator chains (depth 16).
#define KP(a,b) { \
  const float4 hq0 = *(const float4*)(h0f + 2 * kb + 2 * (a)); \
  const float4 hq1 = *(const float4*)(h1f + 2 * kb + 2 * (a)); \
  p1Ae = fmaf(w1_##a, hq0.x, p1Ae); p1Be = fmaf(w1_##a, hq0.y, p1Be); \
  p1Ao = fmaf(w1_##b, hq0.z, p1Ao); p1Bo = fmaf(w1_##b, hq0.w, p1Bo); \
  p1Ae = fmaf(wB_##a, hq1.x, p1Ae); p1Be = fmaf(wB_##a, hq1.y, p1Be); \
  p1Ao = fmaf(wB_##b, hq1.z, p1Ao); p1Bo = fmaf(wB_##b, hq1.w, p1Bo); \
  c0Ae = fmaf(w0_##a, hq0.x, c0Ae); c0Be = fmaf(w0_##a, hq0.y, c0Be); \
  c0Ao = fmaf(w0_##b, hq0.z, c0Ao); c0Bo = fmaf(w0_##b, hq0.w, c0Bo); }

#define PAIRS8(F) F(0,1) F(2,3) F(4,5) F(6,7) F(8,9) F(10,11) F(12,13) F(14,15)

// 256 blocks (1/CU, thread-bound), 1024 threads (16 waves = 4/EU), 2 batches.
// Thread (s=tid>>8, g=tid&255) owns k in [16s,16s+16) of gate row g:
// 50 PINNED weight scalars (whh0/wih1/whh1 16 each + 2 wih0 cols).
// Waves 0-1: layer-0 cell updates; waves 2-3: layer-1. 3 barriers/step.
// All steady-state global traffic: one uniform 8B x-load per wave per batch.
__global__ void __launch_bounds__(1024, 4) lstm2_fused(
    const float* __restrict__ x,
    const float* __restrict__ w_ih0, const float* __restrict__ w_hh0,
    const float* __restrict__ b_ih0, const float* __restrict__ b_hh0,
    const float* __restrict__ w_ih1, const float* __restrict__ w_hh1,
    const float* __restrict__ b_ih1, const float* __restrict__ b_hh1,
    const float* __restrict__ w_out, const float* __restrict__ b_out,
    float* __restrict__ out)
{
  __shared__ float p0[4 * 2 * 256];   // [slice][batch][gate]
  __shared__ float p1[4 * 2 * 256];
  __shared__ float h0f[2 * HH];       // interleaved (A,B) per cell
  __shared__ float h1f[2 * HH];

  const int bb  = blockIdx.x;
  const int tid = threadIdx.x;
  const int g   = tid & 255;          // gate row
  const int s   = tid >> 8;           // k-slice 0..3
  const int kb  = s * 16;

  // ---- one-time: 50 pinned weight scalars ----
  DECLW(w1_) DECLW(w0_) DECLW(wB_)
  LOADW(w1_, w_ih1 + g * HH + kb)
  LOADW(w0_, w_hh0 + g * HH + kb)
  LOADW(wB_, w_hh1 + g * HH + kb)
  float wxc0, wxc1;
  {
    const float2 q = *(const float2*)(w_ih0 + g * DD + 2 * s);
    wxc0 = q.x; wxc1 = q.y;
    PIN(wxc0); PIN(wxc1);
  }
  const float bias0 = (s == 0) ? (b_ih0[g] + b_hh0[g]) : 0.0f;
  const float bias1 = (s == 0) ? (b_ih1[g] + b_hh1[g]) : 0.0f;

  // carried layer-0 partial (my k-slice of Whh0.h0(t-1), + bias on s==0)
  float carA = bias0, carB = bias0;

  // cell state: waves 0-1 own layer-0 cells, waves 2-3 layer-1
  float cst = 0.0f;
  const int cl = tid & 63;
  const int cb = (tid >> 6) & 1;

  if (tid < 128) h1f[tid] = 0.0f;     // h1(-1) = 0 (h0f written before any read)

  // x: this slice's 2 columns, batches A/B (uniform address per wave)
  const float* xA = x + (size_t)(2 * bb) * (TT * DD) + 2 * s;
  const float* xB = xA + TT * DD;
  float2 xqA = *(const float2*)(xA);
  float2 xqB = *(const float2*)(xB);

  __syncthreads();

  for (int t = 0; t < TT; ++t) {
    // ---- phase A: finish layer-0 partial with x(t); publish ----
    {
      float pA = carA, pB = carB;
      pA = fmaf(wxc0, xqA.x, pA); pB = fmaf(wxc0, xqB.x, pB);
      pA = fmaf(wxc1, xqA.y, pA); pB = fmaf(wxc1, xqB.y, pB);
      p0[s * 512 + g]       = pA;
      p0[s * 512 + 256 + g] = pB;
    }
    __syncthreads();  // bar1

    // prefetch x(t+1)
    {
      const int tn = (t + 1 < TT) ? (t + 1) : (TT - 1);
      xqA = *(const float2*)(xA + tn * DD);
      xqB = *(const float2*)(xB + tn * DD);
    }

    // ---- phase B (waves 0-1): layer-0 cell (cb, cl); publish h0 ----
    if (tid < 128) {
      const float pi = ((p0[cb * 256 + cl]        + p0[512 + cb * 256 + cl])
                     +  (p0[1024 + cb * 256 + cl] + p0[1536 + cb * 256 + cl]));
      const float pf = ((p0[cb * 256 + 64 + cl]        + p0[512 + cb * 256 + 64 + cl])
                     +  (p0[1024 + cb * 256 + 64 + cl] + p0[1536 + cb * 256 + 64 + cl]));
      const float pg = ((p0[cb * 256 + 128 + cl]        + p0[512 + cb * 256 + 128 + cl])
                     +  (p0[1024 + cb * 256 + 128 + cl] + p0[1536 + cb * 256 + 128 + cl]));
      const float po = ((p0[cb * 256 + 192 + cl]        + p0[512 + cb * 256 + 192 + cl])
                     +  (p0[1024 + cb * 256 + 192 + cl] + p0[1536 + cb * 256 + 192 + cl]));
      cst = fmaf(sigm(pf), cst, sigm(pi) * tanh_(pg));
      h0f[2 * cl + cb] = sigm(po) * tanh_(cst);
    }
    __syncthreads();  // bar2: h0(t) visible

    // ---- phase C: layer-1 partial + next-step layer-0 Whh0 partial ----
    {
      float p1Ae = bias1, p1Ao = 0.f, p1Be = bias1, p1Bo = 0.f;
      float c0Ae = bias0, c0Ao = 0.f, c0Be = bias0, c0Bo = 0.f;
      PAIRS8(KP)
      p1[s * 512 + g]       = p1Ae + p1Ao;
      p1[s * 512 + 256 + g] = p1Be + p1Bo;
      carA = c0Ae + c0Ao;
      carB = c0Be + c0Bo;
    }
    __syncthreads();  // bar3

    // ---- phase D (waves 2-3): layer-1 cell; publish h1 for next step ----
    if (tid >= 128 && tid < 256) {
      const float pi = ((p1[cb * 256 + cl]        + p1[512 + cb * 256 + cl])
                     +  (p1[1024 + cb * 256 + cl] + p1[1536 + cb * 256 + cl]));
      const float pf = ((p1[cb * 256 + 64 + cl]        + p1[512 + cb * 256 + 64 + cl])
                     +  (p1[1024 + cb * 256 + 64 + cl] + p1[1536 + cb * 256 + 64 + cl]));
      const float pg = ((p1[cb * 256 + 128 + cl]        + p1[512 + cb * 256 + 128 + cl])
                     +  (p1[1024 + cb * 256 + 128 + cl] + p1[1536 + cb * 256 + 128 + cl]));
      const float po = ((p1[cb * 256 + 192 + cl]        + p1[512 + cb * 256 + 192 + cl])
                     +  (p1[1024 + cb * 256 + 192 + cl] + p1[1536 + cb * 256 + 192 + cl]));
      cst = fmaf(sigm(pf), cst, sigm(pi) * tanh_(pg));
      h1f[2 * cl + cb] = sigm(po) * tanh_(cst);
    }
    // no barrier: next step's bar1+bar2 order h1f before its phase-C readers
  }

  __syncthreads();  // final h1 visible

  // ---- head: out[b] = dot(h1, w_out) + b_out ----
  if (tid < 64) {
    const float wv = w_out[tid];
    float vA = h1f[2 * tid]     * wv;
    float vB = h1f[2 * tid + 1] * wv;
#pragma unroll
    for (int off = 32; off; off >>= 1) {
      vA += __shfl_down(vA, off);
      vB += __shfl_down(vB, off);
    }
    if (tid == 0) {
      out[2 * bb]     = vA + b_out[0];
      out[2 * bb + 1] = vB + b_out[0];
    }
  }
}

extern "C" void kernel_launch(void* const* d_in, const int* in_sizes, int n_in,
                              void* d_out, int out_size, void* d_ws, size_t ws_size,
                              hipStream_t stream) {
  const float* x     = (const float*)d_in[0];
  const float* w_ih0 = (const float*)d_in[1];
  const float* w_hh0 = (const float*)d_in[2];
  const float* b_ih0 = (const float*)d_in[3];
  const float* b_hh0 = (const float*)d_in[4];
  const float* w_ih1 = (const float*)d_in[5];
  const float* w_hh1 = (const float*)d_in[6];
  const float* b_ih1 = (const float*)d_in[7];
  const float* b_hh1 = (const float*)d_in[8];
  const float* w_out = (const float*)d_in[9];
  const float* b_out = (const float*)d_in[10];
  float* out = (float*)d_out;

  lstm2_fused<<<dim3(256), dim3(1024), 0, stream>>>(
      x, w_ih0, w_hh0, b_ih0, b_hh0,
      w_ih1, w_hh1, b_ih1, b_hh1,
      w_out, b_out, out);
}